// Round 1
// baseline (5085.368 us; speedup 1.0000x reference)
//
#include <hip/hip_runtime.h>
#include <hip/hip_bf16.h>
#include <math.h>

#define L 4096
#define D 512
#define PP 64
#define HH 128
#define EPSF 1e-8f

// ---------------- norms: ||p_l||, ||h_l|| ----------------
__global__ __launch_bounds__(64) void norms_kernel(const float* __restrict__ fp, const float* __restrict__ fh,
                                                   float* __restrict__ np_, float* __restrict__ nh_) {
  int b = blockIdx.x;
  int which = b >> 12;
  int l = b & (L - 1);
  const float* v = (which ? fh : fp) + (size_t)l * D;
  float s = 0.f;
  for (int i = threadIdx.x; i < D; i += 64) { float x = v[i]; s += x * x; }
  for (int off = 32; off > 0; off >>= 1) s += __shfl_down(s, off);
  if (threadIdx.x == 0) (which ? nh_ : np_)[l] = sqrtf(s);
}

// ---------------- att = (p @ h^T) / clamp(np*nh) ----------------
__global__ __launch_bounds__(256) void att_kernel(const float* __restrict__ A, const float* __restrict__ B,
                                                  const float* __restrict__ np_, const float* __restrict__ nh_,
                                                  float* __restrict__ att) {
  __shared__ float As[64][33];
  __shared__ float Bs[64][33];
  const int t = threadIdx.x;
  const int tc = t & 15, tr = t >> 4;
  const int row0 = blockIdx.y * 64, col0 = blockIdx.x * 64;
  float acc[4][4] = {};
  for (int k0 = 0; k0 < D; k0 += 32) {
#pragma unroll
    for (int i = 0; i < 2; i++) {
      int idx = t + i * 256;            // float4 idx in [0,512)
      int r = idx >> 3, c4 = idx & 7;
      float4 va = *reinterpret_cast<const float4*>(&A[(size_t)(row0 + r) * D + k0 + c4 * 4]);
      float4 vb = *reinterpret_cast<const float4*>(&B[(size_t)(col0 + r) * D + k0 + c4 * 4]);
      As[r][c4 * 4 + 0] = va.x; As[r][c4 * 4 + 1] = va.y; As[r][c4 * 4 + 2] = va.z; As[r][c4 * 4 + 3] = va.w;
      Bs[r][c4 * 4 + 0] = vb.x; Bs[r][c4 * 4 + 1] = vb.y; Bs[r][c4 * 4 + 2] = vb.z; Bs[r][c4 * 4 + 3] = vb.w;
    }
    __syncthreads();
#pragma unroll
    for (int kk = 0; kk < 32; kk++) {
      float a[4], bb[4];
#pragma unroll
      for (int i = 0; i < 4; i++) a[i] = As[tr * 4 + i][kk];
#pragma unroll
      for (int j = 0; j < 4; j++) bb[j] = Bs[tc * 4 + j][kk];
#pragma unroll
      for (int i = 0; i < 4; i++)
#pragma unroll
        for (int j = 0; j < 4; j++) acc[i][j] += a[i] * bb[j];
    }
    __syncthreads();
  }
#pragma unroll
  for (int i = 0; i < 4; i++) {
    int l = row0 + tr * 4 + i;
    float npl = np_[l];
#pragma unroll
    for (int j = 0; j < 4; j++) {
      int cjj = col0 + tc * 4 + j;
      float den = npl * nh_[cjj];
      den = den > EPSF ? den : EPSF;
      att[(size_t)l * L + cjj] = acc[i][j] / den;
    }
  }
}

// ---------------- row sums of att ----------------
__global__ __launch_bounds__(256) void rowsum_kernel(const float* __restrict__ att, float* __restrict__ rs) {
  int row = blockIdx.x;
  float s = 0.f;
  for (int c = threadIdx.x; c < L; c += 256) s += att[(size_t)row * L + c];
  for (int off = 32; off > 0; off >>= 1) s += __shfl_down(s, off);
  __shared__ float ps[4];
  if ((threadIdx.x & 63) == 0) ps[threadIdx.x >> 6] = s;
  __syncthreads();
  if (threadIdx.x == 0) rs[row] = ps[0] + ps[1] + ps[2] + ps[3];
}

// ---------------- column sums of att (2-stage, deterministic) ----------------
__global__ __launch_bounds__(256) void colpart_kernel(const float* __restrict__ att, float* __restrict__ pr) {
  int bx = blockIdx.x & 15, by = blockIdx.x >> 4;
  int col = bx * 256 + threadIdx.x;
  int r0 = by * 64;
  float s = 0.f;
#pragma unroll 8
  for (int r = 0; r < 64; r++) s += att[(size_t)(r0 + r) * L + col];
  pr[(size_t)by * L + col] = s;
}
__global__ __launch_bounds__(256) void colsum_kernel(const float* __restrict__ pr, float* __restrict__ cs) {
  int col = blockIdx.x * 256 + threadIdx.x;
  float s = 0.f;
#pragma unroll 8
  for (int k = 0; k < 64; k++) s += pr[(size_t)k * L + col];
  cs[col] = s;
}

// ---------------- att_mean_h = (att @ h) / clamp(rs) ----------------
__global__ __launch_bounds__(256) void amh_kernel(const float* __restrict__ att, const float* __restrict__ B,
                                                  const float* __restrict__ rs, float* __restrict__ outm) {
  __shared__ float As[64][33];
  __shared__ float Bs[32][65];
  const int t = threadIdx.x;
  const int tc = t & 15, tr = t >> 4;
  const int row0 = blockIdx.y * 64, col0 = blockIdx.x * 64;
  float acc[4][4] = {};
  for (int k0 = 0; k0 < L; k0 += 32) {
#pragma unroll
    for (int i = 0; i < 2; i++) {
      int idx = t + i * 256;
      int r = idx >> 3, c4 = idx & 7;
      float4 va = *reinterpret_cast<const float4*>(&att[(size_t)(row0 + r) * L + k0 + c4 * 4]);
      As[r][c4 * 4 + 0] = va.x; As[r][c4 * 4 + 1] = va.y; As[r][c4 * 4 + 2] = va.z; As[r][c4 * 4 + 3] = va.w;
      int rb = idx >> 4, cb4 = idx & 15;
      float4 vb = *reinterpret_cast<const float4*>(&B[(size_t)(k0 + rb) * D + col0 + cb4 * 4]);
      Bs[rb][cb4 * 4 + 0] = vb.x; Bs[rb][cb4 * 4 + 1] = vb.y; Bs[rb][cb4 * 4 + 2] = vb.z; Bs[rb][cb4 * 4 + 3] = vb.w;
    }
    __syncthreads();
#pragma unroll
    for (int kk = 0; kk < 32; kk++) {
      float a[4], bb[4];
#pragma unroll
      for (int i = 0; i < 4; i++) a[i] = As[tr * 4 + i][kk];
#pragma unroll
      for (int j = 0; j < 4; j++) bb[j] = Bs[kk][tc * 4 + j];
#pragma unroll
      for (int i = 0; i < 4; i++)
#pragma unroll
        for (int j = 0; j < 4; j++) acc[i][j] += a[i] * bb[j];
    }
    __syncthreads();
  }
#pragma unroll
  for (int i = 0; i < 4; i++) {
    int l = row0 + tr * 4 + i;
    float den = rs[l];
    den = den > EPSF ? den : EPSF;
#pragma unroll
    for (int j = 0; j < 4; j++)
      outm[(size_t)l * D + col0 + tc * 4 + j] = acc[i][j] / den;
  }
}

// ---------------- att_mean_p = (att^T @ p) / clamp(cs) ----------------
__global__ __launch_bounds__(256) void amp_kernel(const float* __restrict__ att, const float* __restrict__ B,
                                                  const float* __restrict__ cs, float* __restrict__ outm) {
  __shared__ float As[64][33];
  __shared__ float Bs[32][65];
  const int t = threadIdx.x;
  const int tc = t & 15, tr = t >> 4;
  const int row0 = blockIdx.y * 64, col0 = blockIdx.x * 64;
  float acc[4][4] = {};
  for (int k0 = 0; k0 < L; k0 += 32) {
#pragma unroll
    for (int i = 0; i < 8; i++) {
      int idx = t + i * 256;          // 2048 scalars, coalesced in 64-wide groups
      int k = idx >> 6, jj = idx & 63;
      As[jj][k] = att[(size_t)(k0 + k) * L + row0 + jj];
    }
#pragma unroll
    for (int i = 0; i < 2; i++) {
      int idx = t + i * 256;
      int rb = idx >> 4, cb4 = idx & 15;
      float4 vb = *reinterpret_cast<const float4*>(&B[(size_t)(k0 + rb) * D + col0 + cb4 * 4]);
      Bs[rb][cb4 * 4 + 0] = vb.x; Bs[rb][cb4 * 4 + 1] = vb.y; Bs[rb][cb4 * 4 + 2] = vb.z; Bs[rb][cb4 * 4 + 3] = vb.w;
    }
    __syncthreads();
#pragma unroll
    for (int kk = 0; kk < 32; kk++) {
      float a[4], bb[4];
#pragma unroll
      for (int i = 0; i < 4; i++) a[i] = As[tr * 4 + i][kk];
#pragma unroll
      for (int j = 0; j < 4; j++) bb[j] = Bs[kk][tc * 4 + j];
#pragma unroll
      for (int i = 0; i < 4; i++)
#pragma unroll
        for (int j = 0; j < 4; j++) acc[i][j] += a[i] * bb[j];
    }
    __syncthreads();
  }
#pragma unroll
  for (int i = 0; i < 4; i++) {
    int jrow = row0 + tr * 4 + i;
    float den = cs[jrow];
    den = den > EPSF ? den : EPSF;
#pragma unroll
    for (int j = 0; j < 4; j++)
      outm[(size_t)jrow * D + col0 + tc * 4 + j] = acc[i][j] / den;
  }
}

// ---------------- w2 transposed: w2t[d][p] = mp_w[p][d]^2 ----------------
__global__ void w2t_kernel(const float* __restrict__ mpw, float* __restrict__ w2t) {
  int o = blockIdx.x * blockDim.x + threadIdx.x;
  if (o >= PP * D) return;
  int dd = o >> 6, p = o & 63;
  float v = mpw[(size_t)p * D + dd];
  w2t[o] = v * v;
}

// ---------------- multi-perspective weighted cosine ----------------
__global__ __launch_bounds__(64) void match_kernel(const float* __restrict__ fp, const float* __restrict__ fh,
                                                   const float* __restrict__ amh, const float* __restrict__ amp,
                                                   const float* __restrict__ w2t,
                                                   float* __restrict__ match_p, float* __restrict__ match_h) {
  int b = blockIdx.x;
  int which = b >> 12;
  int l = b & (L - 1);
  const float* v1 = (which ? fh : fp) + (size_t)l * D;
  const float* v2 = (which ? amp : amh) + (size_t)l * D;
  __shared__ float s1[D], s2[D];
  int t = threadIdx.x;
#pragma unroll
  for (int i = 0; i < 2; i++) {
    int f4 = t + 64 * i;
    *reinterpret_cast<float4*>(&s1[f4 * 4]) = *reinterpret_cast<const float4*>(&v1[f4 * 4]);
    *reinterpret_cast<float4*>(&s2[f4 * 4]) = *reinterpret_cast<const float4*>(&v2[f4 * 4]);
  }
  __syncthreads();
  float num = 0.f, a1 = 0.f, a2 = 0.f;
  for (int dd = 0; dd < D; dd++) {
    float wv = w2t[dd * PP + t];
    float x = s1[dd], y = s2[dd];
    num += wv * x * y;
    a1 += wv * x * x;
    a2 += wv * y * y;
  }
  float n1 = fmaxf(sqrtf(a1), EPSF), n2 = fmaxf(sqrtf(a2), EPSF);
  float* outm = which ? match_h : match_p;
  outm[(size_t)l * PP + t] = num / (n1 * n2);
}

// ---------------- gx = match @ w_ih^T + (b_ih + b_hh), time-reversed for odd dirs ----------------
__global__ __launch_bounds__(512) void gx_kernel(const float* __restrict__ match_p, const float* __restrict__ match_h,
                                                 const float* __restrict__ wih_f, const float* __restrict__ wih_r,
                                                 const float* __restrict__ bih_f, const float* __restrict__ bhh_f,
                                                 const float* __restrict__ bih_r, const float* __restrict__ bhh_r,
                                                 float* __restrict__ gx) {
  int b = blockIdx.x;
  int dir = b >> 9;
  int chunk = b & 511;
  const float* m_src = (dir < 2) ? match_p : match_h;
  const float* wih = (dir & 1) ? wih_r : wih_f;
  const float* bi = (dir & 1) ? bih_r : bih_f;
  const float* bh = (dir & 1) ? bhh_r : bhh_f;
  __shared__ float m[8][PP];
  int t = threadIdx.x;
  {
    int tt = t >> 6, p = t & 63;
    int tstep = chunk * 8 + tt;
    int row = (dir & 1) ? (L - 1 - tstep) : tstep;
    m[tt][p] = m_src[(size_t)row * PP + p];
  }
  __syncthreads();
  int j = t;
  float bias = bi[j] + bh[j];
  float acc[8];
#pragma unroll
  for (int tt = 0; tt < 8; tt++) acc[tt] = bias;
  for (int p = 0; p < PP; p++) {
    float wv = wih[(size_t)j * PP + p];
#pragma unroll
    for (int tt = 0; tt < 8; tt++) acc[tt] += wv * m[tt][p];
  }
#pragma unroll
  for (int tt = 0; tt < 8; tt++)
    gx[((size_t)dir * L + chunk * 8 + tt) * 512 + j] = acc[tt];
}

// ---------------- 4 sequential LSTMs (persistent blocks) ----------------
__global__ __launch_bounds__(512, 2) void lstm_kernel(const float* __restrict__ gx,
                                                      const float* __restrict__ whh_f, const float* __restrict__ whh_r,
                                                      float* __restrict__ out) {
  const int dir = blockIdx.x;
  const float* __restrict__ whh = (dir & 1) ? whh_r : whh_f;
  const int j = threadIdx.x;
  float w[128];
#pragma unroll
  for (int k = 0; k < 128; k++) w[k] = whh[(size_t)j * 128 + k];
  __shared__ float h_sh[128];
  __shared__ float act[512];
  float c = 0.f;
  if (j < 128) h_sh[j] = 0.f;
  __syncthreads();
  const float* __restrict__ g = gx + (size_t)dir * L * 512;
  float gval = g[j];
  for (int t = 0; t < L; t++) {
    float gnext = (t + 1 < L) ? g[(size_t)(t + 1) * 512 + j] : 0.f;
    float d0 = 0.f, d1 = 0.f, d2 = 0.f, d3 = 0.f;
#pragma unroll
    for (int k = 0; k < 128; k += 4) {
      d0 += w[k]     * h_sh[k];
      d1 += w[k + 1] * h_sh[k + 1];
      d2 += w[k + 2] * h_sh[k + 2];
      d3 += w[k + 3] * h_sh[k + 3];
    }
    float z = gval + ((d0 + d1) + (d2 + d3));
    float a = ((j >> 7) == 2) ? tanhf(z) : (1.f / (1.f + expf(-z)));
    act[j] = a;
    __syncthreads();
    if (j < 128) {
      c = act[128 + j] * c + act[j] * act[256 + j];
      h_sh[j] = act[384 + j] * tanhf(c);
    }
    __syncthreads();
    gval = gnext;
  }
  if (j < 128) out[dir * 128 + j] = h_sh[j];
}

extern "C" void kernel_launch(void* const* d_in, const int* in_sizes, int n_in,
                              void* d_out, int out_size, void* d_ws, size_t ws_size,
                              hipStream_t stream) {
  const float* fp    = (const float*)d_in[0];
  const float* fh    = (const float*)d_in[1];
  const float* mpw   = (const float*)d_in[2];
  const float* wih_f = (const float*)d_in[3];
  const float* whh_f = (const float*)d_in[4];
  const float* bih_f = (const float*)d_in[5];
  const float* bhh_f = (const float*)d_in[6];
  const float* wih_r = (const float*)d_in[7];
  const float* whh_r = (const float*)d_in[8];
  const float* bih_r = (const float*)d_in[9];
  const float* bhh_r = (const float*)d_in[10];
  float* out = (float*)d_out;
  float* ws = (float*)d_ws;

  // workspace layout (floats)
  size_t np_off  = 0;                       // 4096
  size_t nh_off  = np_off + L;              // 4096
  size_t rs_off  = nh_off + L;              // 4096
  size_t cs_off  = rs_off + L;              // 4096
  size_t w2_off  = cs_off + L;              // 32768
  size_t amh_off = w2_off + (size_t)PP * D; // 2097152
  size_t amp_off = amh_off + (size_t)L * D; // 2097152
  size_t mp_off  = amp_off + (size_t)L * D; // 262144
  size_t mh_off  = mp_off + (size_t)L * PP; // 262144
  size_t pr_off  = mh_off + (size_t)L * PP; // 262144 (64 x 4096)
  size_t att_off = pr_off + (size_t)64 * L; // 16777216
  size_t gx_off  = att_off;                 // alias: gx (8388608) reuses dead att region
  size_t total   = att_off + (size_t)L * L;
  if (ws_size < total * sizeof(float)) return;  // workspace too small — bail safely

  float* np_  = ws + np_off;
  float* nh_  = ws + nh_off;
  float* rs   = ws + rs_off;
  float* cs   = ws + cs_off;
  float* w2t  = ws + w2_off;
  float* amh  = ws + amh_off;
  float* amp  = ws + amp_off;
  float* mtp  = ws + mp_off;
  float* mth  = ws + mh_off;
  float* pr   = ws + pr_off;
  float* att  = ws + att_off;
  float* gx   = ws + gx_off;

  norms_kernel<<<2 * L, 64, 0, stream>>>(fp, fh, np_, nh_);
  att_kernel<<<dim3(64, 64), 256, 0, stream>>>(fp, fh, np_, nh_, att);
  rowsum_kernel<<<L, 256, 0, stream>>>(att, rs);
  colpart_kernel<<<1024, 256, 0, stream>>>(att, pr);
  colsum_kernel<<<16, 256, 0, stream>>>(pr, cs);
  amh_kernel<<<dim3(8, 64), 256, 0, stream>>>(att, fh, rs, amh);
  amp_kernel<<<dim3(8, 64), 256, 0, stream>>>(att, fp, cs, amp);
  w2t_kernel<<<(PP * D + 255) / 256, 256, 0, stream>>>(mpw, w2t);
  match_kernel<<<2 * L, 64, 0, stream>>>(fp, fh, amh, amp, w2t, mtp, mth);
  gx_kernel<<<4 * (L / 8), 512, 0, stream>>>(mtp, mth, wih_f, wih_r, bih_f, bhh_f, bih_r, bhh_r, gx);
  lstm_kernel<<<4, 512, 0, stream>>>(gx, whh_f, whh_r, out);
}

// Round 2
// 4577.243 us; speedup vs baseline: 1.1110x; 1.1110x over previous
//
#include <hip/hip_runtime.h>
#include <hip/hip_bf16.h>
#include <math.h>

#define L 4096
#define D 512
#define PP 64
#define HH 128
#define EPSF 1e-8f

// ---------------- norms: ||p_l||, ||h_l|| ----------------
__global__ __launch_bounds__(64) void norms_kernel(const float* __restrict__ fp, const float* __restrict__ fh,
                                                   float* __restrict__ np_, float* __restrict__ nh_) {
  int b = blockIdx.x;
  int which = b >> 12;
  int l = b & (L - 1);
  const float* v = (which ? fh : fp) + (size_t)l * D;
  float s = 0.f;
  for (int i = threadIdx.x; i < D; i += 64) { float x = v[i]; s += x * x; }
  for (int off = 32; off > 0; off >>= 1) s += __shfl_down(s, off);
  if (threadIdx.x == 0) (which ? nh_ : np_)[l] = sqrtf(s);
}

// ---------------- att = (p @ h^T) / clamp(np*nh) ----------------
__global__ __launch_bounds__(256) void att_kernel(const float* __restrict__ A, const float* __restrict__ B,
                                                  const float* __restrict__ np_, const float* __restrict__ nh_,
                                                  float* __restrict__ att) {
  __shared__ float As[64][33];
  __shared__ float Bs[64][33];
  const int t = threadIdx.x;
  const int tc = t & 15, tr = t >> 4;
  const int row0 = blockIdx.y * 64, col0 = blockIdx.x * 64;
  float acc[4][4] = {};
  for (int k0 = 0; k0 < D; k0 += 32) {
#pragma unroll
    for (int i = 0; i < 2; i++) {
      int idx = t + i * 256;            // float4 idx in [0,512)
      int r = idx >> 3, c4 = idx & 7;
      float4 va = *reinterpret_cast<const float4*>(&A[(size_t)(row0 + r) * D + k0 + c4 * 4]);
      float4 vb = *reinterpret_cast<const float4*>(&B[(size_t)(col0 + r) * D + k0 + c4 * 4]);
      As[r][c4 * 4 + 0] = va.x; As[r][c4 * 4 + 1] = va.y; As[r][c4 * 4 + 2] = va.z; As[r][c4 * 4 + 3] = va.w;
      Bs[r][c4 * 4 + 0] = vb.x; Bs[r][c4 * 4 + 1] = vb.y; Bs[r][c4 * 4 + 2] = vb.z; Bs[r][c4 * 4 + 3] = vb.w;
    }
    __syncthreads();
#pragma unroll
    for (int kk = 0; kk < 32; kk++) {
      float a[4], bb[4];
#pragma unroll
      for (int i = 0; i < 4; i++) a[i] = As[tr * 4 + i][kk];
#pragma unroll
      for (int j = 0; j < 4; j++) bb[j] = Bs[tc * 4 + j][kk];
#pragma unroll
      for (int i = 0; i < 4; i++)
#pragma unroll
        for (int j = 0; j < 4; j++) acc[i][j] += a[i] * bb[j];
    }
    __syncthreads();
  }
#pragma unroll
  for (int i = 0; i < 4; i++) {
    int l = row0 + tr * 4 + i;
    float npl = np_[l];
#pragma unroll
    for (int j = 0; j < 4; j++) {
      int cjj = col0 + tc * 4 + j;
      float den = npl * nh_[cjj];
      den = den > EPSF ? den : EPSF;
      att[(size_t)l * L + cjj] = acc[i][j] / den;
    }
  }
}

// ---------------- row sums of att ----------------
__global__ __launch_bounds__(256) void rowsum_kernel(const float* __restrict__ att, float* __restrict__ rs) {
  int row = blockIdx.x;
  float s = 0.f;
  for (int c = threadIdx.x; c < L; c += 256) s += att[(size_t)row * L + c];
  for (int off = 32; off > 0; off >>= 1) s += __shfl_down(s, off);
  __shared__ float ps[4];
  if ((threadIdx.x & 63) == 0) ps[threadIdx.x >> 6] = s;
  __syncthreads();
  if (threadIdx.x == 0) rs[row] = ps[0] + ps[1] + ps[2] + ps[3];
}

// ---------------- column sums of att (2-stage, deterministic) ----------------
__global__ __launch_bounds__(256) void colpart_kernel(const float* __restrict__ att, float* __restrict__ pr) {
  int bx = blockIdx.x & 15, by = blockIdx.x >> 4;
  int col = bx * 256 + threadIdx.x;
  int r0 = by * 64;
  float s = 0.f;
#pragma unroll 8
  for (int r = 0; r < 64; r++) s += att[(size_t)(r0 + r) * L + col];
  pr[(size_t)by * L + col] = s;
}
__global__ __launch_bounds__(256) void colsum_kernel(const float* __restrict__ pr, float* __restrict__ cs) {
  int col = blockIdx.x * 256 + threadIdx.x;
  float s = 0.f;
#pragma unroll 8
  for (int k = 0; k < 64; k++) s += pr[(size_t)k * L + col];
  cs[col] = s;
}

// ---------------- att_mean_h = (att @ h) / clamp(rs) ----------------
__global__ __launch_bounds__(256) void amh_kernel(const float* __restrict__ att, const float* __restrict__ B,
                                                  const float* __restrict__ rs, float* __restrict__ outm) {
  __shared__ float As[64][33];
  __shared__ float Bs[32][65];
  const int t = threadIdx.x;
  const int tc = t & 15, tr = t >> 4;
  const int row0 = blockIdx.y * 64, col0 = blockIdx.x * 64;
  float acc[4][4] = {};
  for (int k0 = 0; k0 < L; k0 += 32) {
#pragma unroll
    for (int i = 0; i < 2; i++) {
      int idx = t + i * 256;
      int r = idx >> 3, c4 = idx & 7;
      float4 va = *reinterpret_cast<const float4*>(&att[(size_t)(row0 + r) * L + k0 + c4 * 4]);
      As[r][c4 * 4 + 0] = va.x; As[r][c4 * 4 + 1] = va.y; As[r][c4 * 4 + 2] = va.z; As[r][c4 * 4 + 3] = va.w;
      int rb = idx >> 4, cb4 = idx & 15;
      float4 vb = *reinterpret_cast<const float4*>(&B[(size_t)(k0 + rb) * D + col0 + cb4 * 4]);
      Bs[rb][cb4 * 4 + 0] = vb.x; Bs[rb][cb4 * 4 + 1] = vb.y; Bs[rb][cb4 * 4 + 2] = vb.z; Bs[rb][cb4 * 4 + 3] = vb.w;
    }
    __syncthreads();
#pragma unroll
    for (int kk = 0; kk < 32; kk++) {
      float a[4], bb[4];
#pragma unroll
      for (int i = 0; i < 4; i++) a[i] = As[tr * 4 + i][kk];
#pragma unroll
      for (int j = 0; j < 4; j++) bb[j] = Bs[kk][tc * 4 + j];
#pragma unroll
      for (int i = 0; i < 4; i++)
#pragma unroll
        for (int j = 0; j < 4; j++) acc[i][j] += a[i] * bb[j];
    }
    __syncthreads();
  }
#pragma unroll
  for (int i = 0; i < 4; i++) {
    int l = row0 + tr * 4 + i;
    float den = rs[l];
    den = den > EPSF ? den : EPSF;
#pragma unroll
    for (int j = 0; j < 4; j++)
      outm[(size_t)l * D + col0 + tc * 4 + j] = acc[i][j] / den;
  }
}

// ---------------- att_mean_p = (att^T @ p) / clamp(cs) ----------------
__global__ __launch_bounds__(256) void amp_kernel(const float* __restrict__ att, const float* __restrict__ B,
                                                  const float* __restrict__ cs, float* __restrict__ outm) {
  __shared__ float As[64][33];
  __shared__ float Bs[32][65];
  const int t = threadIdx.x;
  const int tc = t & 15, tr = t >> 4;
  const int row0 = blockIdx.y * 64, col0 = blockIdx.x * 64;
  float acc[4][4] = {};
  for (int k0 = 0; k0 < L; k0 += 32) {
#pragma unroll
    for (int i = 0; i < 8; i++) {
      int idx = t + i * 256;          // 2048 scalars, coalesced in 64-wide groups
      int k = idx >> 6, jj = idx & 63;
      As[jj][k] = att[(size_t)(k0 + k) * L + row0 + jj];
    }
#pragma unroll
    for (int i = 0; i < 2; i++) {
      int idx = t + i * 256;
      int rb = idx >> 4, cb4 = idx & 15;
      float4 vb = *reinterpret_cast<const float4*>(&B[(size_t)(k0 + rb) * D + col0 + cb4 * 4]);
      Bs[rb][cb4 * 4 + 0] = vb.x; Bs[rb][cb4 * 4 + 1] = vb.y; Bs[rb][cb4 * 4 + 2] = vb.z; Bs[rb][cb4 * 4 + 3] = vb.w;
    }
    __syncthreads();
#pragma unroll
    for (int kk = 0; kk < 32; kk++) {
      float a[4], bb[4];
#pragma unroll
      for (int i = 0; i < 4; i++) a[i] = As[tr * 4 + i][kk];
#pragma unroll
      for (int j = 0; j < 4; j++) bb[j] = Bs[kk][tc * 4 + j];
#pragma unroll
      for (int i = 0; i < 4; i++)
#pragma unroll
        for (int j = 0; j < 4; j++) acc[i][j] += a[i] * bb[j];
    }
    __syncthreads();
  }
#pragma unroll
  for (int i = 0; i < 4; i++) {
    int jrow = row0 + tr * 4 + i;
    float den = cs[jrow];
    den = den > EPSF ? den : EPSF;
#pragma unroll
    for (int j = 0; j < 4; j++)
      outm[(size_t)jrow * D + col0 + tc * 4 + j] = acc[i][j] / den;
  }
}

// ---------------- w2 transposed: w2t[d][p] = mp_w[p][d]^2 ----------------
__global__ void w2t_kernel(const float* __restrict__ mpw, float* __restrict__ w2t) {
  int o = blockIdx.x * blockDim.x + threadIdx.x;
  if (o >= PP * D) return;
  int dd = o >> 6, p = o & 63;
  float v = mpw[(size_t)p * D + dd];
  w2t[o] = v * v;
}

// ---------------- multi-perspective weighted cosine ----------------
__global__ __launch_bounds__(64) void match_kernel(const float* __restrict__ fp, const float* __restrict__ fh,
                                                   const float* __restrict__ amh, const float* __restrict__ amp,
                                                   const float* __restrict__ w2t,
                                                   float* __restrict__ match_p, float* __restrict__ match_h) {
  int b = blockIdx.x;
  int which = b >> 12;
  int l = b & (L - 1);
  const float* v1 = (which ? fh : fp) + (size_t)l * D;
  const float* v2 = (which ? amp : amh) + (size_t)l * D;
  __shared__ float s1[D], s2[D];
  int t = threadIdx.x;
#pragma unroll
  for (int i = 0; i < 2; i++) {
    int f4 = t + 64 * i;
    *reinterpret_cast<float4*>(&s1[f4 * 4]) = *reinterpret_cast<const float4*>(&v1[f4 * 4]);
    *reinterpret_cast<float4*>(&s2[f4 * 4]) = *reinterpret_cast<const float4*>(&v2[f4 * 4]);
  }
  __syncthreads();
  float num = 0.f, a1 = 0.f, a2 = 0.f;
  for (int dd = 0; dd < D; dd++) {
    float wv = w2t[dd * PP + t];
    float x = s1[dd], y = s2[dd];
    num += wv * x * y;
    a1 += wv * x * x;
    a2 += wv * y * y;
  }
  float n1 = fmaxf(sqrtf(a1), EPSF), n2 = fmaxf(sqrtf(a2), EPSF);
  float* outm = which ? match_h : match_p;
  outm[(size_t)l * PP + t] = num / (n1 * n2);
}

// ---------------- gx = match @ w_ih^T + (b_ih + b_hh), time-reversed for odd dirs ----------------
__global__ __launch_bounds__(512) void gx_kernel(const float* __restrict__ match_p, const float* __restrict__ match_h,
                                                 const float* __restrict__ wih_f, const float* __restrict__ wih_r,
                                                 const float* __restrict__ bih_f, const float* __restrict__ bhh_f,
                                                 const float* __restrict__ bih_r, const float* __restrict__ bhh_r,
                                                 float* __restrict__ gx) {
  int b = blockIdx.x;
  int dir = b >> 9;
  int chunk = b & 511;
  const float* m_src = (dir < 2) ? match_p : match_h;
  const float* wih = (dir & 1) ? wih_r : wih_f;
  const float* bi = (dir & 1) ? bih_r : bih_f;
  const float* bh = (dir & 1) ? bhh_r : bhh_f;
  __shared__ float m[8][PP];
  int t = threadIdx.x;
  {
    int tt = t >> 6, p = t & 63;
    int tstep = chunk * 8 + tt;
    int row = (dir & 1) ? (L - 1 - tstep) : tstep;
    m[tt][p] = m_src[(size_t)row * PP + p];
  }
  __syncthreads();
  int j = t;
  float bias = bi[j] + bh[j];
  float acc[8];
#pragma unroll
  for (int tt = 0; tt < 8; tt++) acc[tt] = bias;
  for (int p = 0; p < PP; p++) {
    float wv = wih[(size_t)j * PP + p];
#pragma unroll
    for (int tt = 0; tt < 8; tt++) acc[tt] += wv * m[tt][p];
  }
#pragma unroll
  for (int tt = 0; tt < 8; tt++)
    gx[((size_t)dir * L + chunk * 8 + tt) * 512 + j] = acc[tt];
}

// ---------------- 4 sequential LSTMs (persistent blocks) ----------------
// Layout: 512 threads = 8 waves. Lane group of 8 (g = lane&7) owns 8 outputs
// jbase..jbase+7 (jbase = tid & ~7); lane g holds weights for k in [g*16, g*16+16)
// of all 8 outputs -> 32 float4 = 128 VGPRs, pinned via asm so the allocator
// cannot sink the global loads into the 4096-step loop (round-0 failure mode:
// VGPR=80, weights re-read from L2 every step = 2048 cyc/step).
__global__ __launch_bounds__(512, 2) void lstm_kernel(const float* __restrict__ gx,
                                                      const float* __restrict__ whh_f, const float* __restrict__ whh_r,
                                                      float* __restrict__ out) {
  const int dir = blockIdx.x;
  const float* __restrict__ whh = (dir & 1) ? whh_r : whh_f;
  const int tid = threadIdx.x;
  const int lane = tid & 63;
  const int g = lane & 7;            // k-segment index
  const int jbase = tid & ~7;        // first output of this 8-lane group

  float4 w4[8][4];
#pragma unroll
  for (int jj = 0; jj < 8; jj++)
#pragma unroll
    for (int q = 0; q < 4; q++)
      w4[jj][q] = *reinterpret_cast<const float4*>(&whh[(size_t)(jbase + jj) * HH + g * 16 + q * 4]);
#pragma unroll
  for (int jj = 0; jj < 8; jj++)
#pragma unroll
    for (int q = 0; q < 4; q++)
      asm volatile("" : "+v"(w4[jj][q].x), "+v"(w4[jj][q].y), "+v"(w4[jj][q].z), "+v"(w4[jj][q].w));

  __shared__ __align__(16) float h_sh[HH];
  __shared__ float act[512];
  float c = 0.f;
  if (tid < HH) h_sh[tid] = 0.f;
  __syncthreads();

  const float* __restrict__ gsrc = gx + (size_t)dir * L * 512;
  float gval = gsrc[tid];
  const int m = tid & 127;
  const int is_g_gate = ((tid >> 7) == 2);
  const int b0 = g & 1, b1 = g & 2, b2 = g & 4;
  float h = 0.f;

  for (int t = 0; t < L; t++) {
    float gnext = (t + 1 < L) ? gsrc[(size_t)(t + 1) * 512 + tid] : 0.f;
    // h fragment for my k-segment (broadcast among the 8 groups per wave)
    float4 hf[4];
#pragma unroll
    for (int q = 0; q < 4; q++)
      hf[q] = *reinterpret_cast<const float4*>(&h_sh[g * 16 + q * 4]);
    // 8 outputs x 16 k  (all operands in VGPRs)
    float acc[8];
#pragma unroll
    for (int jj = 0; jj < 8; jj++) {
      float s0 = w4[jj][0].x * hf[0].x;
      float s1 = w4[jj][0].y * hf[0].y;
      s0 = fmaf(w4[jj][0].z, hf[0].z, s0);
      s1 = fmaf(w4[jj][0].w, hf[0].w, s1);
#pragma unroll
      for (int q = 1; q < 4; q++) {
        s0 = fmaf(w4[jj][q].x, hf[q].x, s0);
        s1 = fmaf(w4[jj][q].y, hf[q].y, s1);
        s0 = fmaf(w4[jj][q].z, hf[q].z, s0);
        s1 = fmaf(w4[jj][q].w, hf[q].w, s1);
      }
      acc[jj] = s0 + s1;
    }
    // compacting butterfly within the 8-lane group: 7 shuffles, leaves
    // the full dot for output (jbase+g)==tid on this lane
    float r4[4];
#pragma unroll
    for (int i = 0; i < 4; i++) {
      float keep = b0 ? acc[2 * i + 1] : acc[2 * i];
      float send = b0 ? acc[2 * i] : acc[2 * i + 1];
      r4[i] = keep + __shfl_xor(send, 1);
    }
    float r2[2];
#pragma unroll
    for (int u = 0; u < 2; u++) {
      float keep = b1 ? r4[2 * u + 1] : r4[2 * u];
      float send = b1 ? r4[2 * u] : r4[2 * u + 1];
      r2[u] = keep + __shfl_xor(send, 2);
    }
    float keepf = b2 ? r2[1] : r2[0];
    float sendf = b2 ? r2[0] : r2[1];
    float z = keepf + __shfl_xor(sendf, 4) + gval;
    // activation (wave-uniform branch: gate = tid>>7)
    float a;
    if (is_g_gate) {
      float e = __expf(2.f * z);
      a = 1.f - 2.f / (e + 1.f);
    } else {
      a = 1.f / (1.f + __expf(-z));
    }
    act[tid] = a;
    __syncthreads();
    // c/h update computed redundantly by all 512 threads (no idle waves)
    float iv = act[m], fv = act[HH + m], gv = act[2 * HH + m], ov = act[3 * HH + m];
    c = fv * c + iv * gv;
    float e2 = __expf(2.f * c);
    h = ov * (1.f - 2.f / (e2 + 1.f));
    if (tid < HH) h_sh[tid] = h;
    __syncthreads();
    gval = gnext;
  }
  if (tid < HH) out[dir * HH + tid] = h;
}

extern "C" void kernel_launch(void* const* d_in, const int* in_sizes, int n_in,
                              void* d_out, int out_size, void* d_ws, size_t ws_size,
                              hipStream_t stream) {
  const float* fp    = (const float*)d_in[0];
  const float* fh    = (const float*)d_in[1];
  const float* mpw   = (const float*)d_in[2];
  const float* wih_f = (const float*)d_in[3];
  const float* whh_f = (const float*)d_in[4];
  const float* bih_f = (const float*)d_in[5];
  const float* bhh_f = (const float*)d_in[6];
  const float* wih_r = (const float*)d_in[7];
  const float* whh_r = (const float*)d_in[8];
  const float* bih_r = (const float*)d_in[9];
  const float* bhh_r = (const float*)d_in[10];
  float* out = (float*)d_out;
  float* ws = (float*)d_ws;

  // workspace layout (floats)
  size_t np_off  = 0;                       // 4096
  size_t nh_off  = np_off + L;              // 4096
  size_t rs_off  = nh_off + L;              // 4096
  size_t cs_off  = rs_off + L;              // 4096
  size_t w2_off  = cs_off + L;              // 32768
  size_t amh_off = w2_off + (size_t)PP * D; // 2097152
  size_t amp_off = amh_off + (size_t)L * D; // 2097152
  size_t mp_off  = amp_off + (size_t)L * D; // 262144
  size_t mh_off  = mp_off + (size_t)L * PP; // 262144
  size_t pr_off  = mh_off + (size_t)L * PP; // 262144 (64 x 4096)
  size_t att_off = pr_off + (size_t)64 * L; // 16777216
  size_t gx_off  = att_off;                 // alias: gx (8388608) reuses dead att region
  size_t total   = att_off + (size_t)L * L;
  if (ws_size < total * sizeof(float)) return;  // workspace too small — bail safely

  float* np_  = ws + np_off;
  float* nh_  = ws + nh_off;
  float* rs   = ws + rs_off;
  float* cs   = ws + cs_off;
  float* w2t  = ws + w2_off;
  float* amh  = ws + amh_off;
  float* amp  = ws + amp_off;
  float* mtp  = ws + mp_off;
  float* mth  = ws + mh_off;
  float* pr   = ws + pr_off;
  float* att  = ws + att_off;
  float* gx   = ws + gx_off;

  norms_kernel<<<2 * L, 64, 0, stream>>>(fp, fh, np_, nh_);
  att_kernel<<<dim3(64, 64), 256, 0, stream>>>(fp, fh, np_, nh_, att);
  rowsum_kernel<<<L, 256, 0, stream>>>(att, rs);
  colpart_kernel<<<1024, 256, 0, stream>>>(att, pr);
  colsum_kernel<<<16, 256, 0, stream>>>(pr, cs);
  amh_kernel<<<dim3(8, 64), 256, 0, stream>>>(att, fh, rs, amh);
  amp_kernel<<<dim3(8, 64), 256, 0, stream>>>(att, fp, cs, amp);
  w2t_kernel<<<(PP * D + 255) / 256, 256, 0, stream>>>(mpw, w2t);
  match_kernel<<<2 * L, 64, 0, stream>>>(fp, fh, amh, amp, w2t, mtp, mth);
  gx_kernel<<<4 * (L / 8), 512, 0, stream>>>(mtp, mth, wih_f, wih_r, bih_f, bhh_f, bih_r, bhh_r, gx);
  lstm_kernel<<<4, 512, 0, stream>>>(gx, whh_f, whh_r, out);
}